// Round 2
// 434.567 us; speedup vs baseline: 1.0368x; 1.0368x over previous
//
#include <hip/hip_runtime.h>

#define TPB 256

// clang native vector type — __builtin_nontemporal_* accepts this (not
// HIP_vector_type<float,4>, which is a class and was R1's compile failure).
typedef float f4 __attribute__((ext_vector_type(4)));

__device__ __forceinline__ float fast_tanh(float a) {
    // tanh(a) = 1 - 2/(1 + exp(2a)); saturates cleanly at +-1 for |a| large.
    float e = __expf(2.0f * a);
    float r = __builtin_amdgcn_rcpf(e + 1.0f);
    return fmaf(-2.0f, r, 1.0f);
}

__device__ __forceinline__ float fast_sig10(float h) {
    // sigmoid(10h) = 1/(1 + exp(-10h))
    float e = __expf(-10.0f * h);
    return __builtin_amdgcn_rcpf(1.0f + e);
}

// One thread handles TWO consecutive batch elements (4 recurrence chains),
// so each time step is a single coalesced 16B load + 16B store.
// Depth-4 software-pipelined prefetch: 4 time steps of x held in named
// registers (static indexing only — runtime-indexed arrays go to scratch),
// so ~64 B/thread stay in flight and the ~900-cycle HBM latency is covered
// by 4 steps of compute instead of 1. Nontemporal hints on the x/out
// streams (538 MB streamed once; don't thrash L2/L3).
__global__ __launch_bounds__(TPB) void Pixel_RNNcontrol_75453985456217_kernel(
    const float* __restrict__ x,     // (T, B, 2)
    const float* __restrict__ h0,    // (1, B, 2)
    const float* __restrict__ W_ih,  // (2, 2) row-major
    const float* __restrict__ W_hh,  // (2, 2) row-major
    const float* __restrict__ b_ih,  // (2,)
    const float* __restrict__ b_hh,  // (2,)
    float* __restrict__ out,         // out (T,B,2) followed by hidden (B,2)
    int T, int B)
{
    int p = blockIdx.x * TPB + threadIdx.x;   // pair index
    const int npairs = B >> 1;
    if (p >= npairs) return;

    // Uniform weights (broadcast loads, L2-resident)
    const float w00 = W_ih[0], w01 = W_ih[1], w10 = W_ih[2], w11 = W_ih[3];
    const float u00 = W_hh[0], u01 = W_hh[1], u10 = W_hh[2], u11 = W_hh[3];
    const float bias0 = b_ih[0] + b_hh[0];
    const float bias1 = b_ih[1] + b_hh[1];

    const f4* x4   = (const f4*)x;
    f4*       out4 = (f4*)out;
    const size_t s = (size_t)npairs;          // f4s per time step

    f4 hv = ((const f4*)h0)[p];
    float ha0 = hv.x, ha1 = hv.y;   // batch elem 2p
    float hb0 = hv.z, hb1 = hv.w;   // batch elem 2p+1

    size_t idx = (size_t)p;

    // One recurrence step: consume xv, advance h, store sigmoid(10h), idx += s.
#define STEP(xv) do { \
        float aa0 = fmaf((xv).x, w00, fmaf((xv).y, w01, fmaf(ha0, u00, fmaf(ha1, u01, bias0)))); \
        float aa1 = fmaf((xv).x, w10, fmaf((xv).y, w11, fmaf(ha0, u10, fmaf(ha1, u11, bias1)))); \
        float ab0 = fmaf((xv).z, w00, fmaf((xv).w, w01, fmaf(hb0, u00, fmaf(hb1, u01, bias0)))); \
        float ab1 = fmaf((xv).z, w10, fmaf((xv).w, w11, fmaf(hb0, u10, fmaf(hb1, u11, bias1)))); \
        ha0 = fast_tanh(aa0); ha1 = fast_tanh(aa1); \
        hb0 = fast_tanh(ab0); hb1 = fast_tanh(ab1); \
        f4 ov; \
        ov.x = fast_sig10(ha0); ov.y = fast_sig10(ha1); \
        ov.z = fast_sig10(hb0); ov.w = fast_sig10(hb1); \
        __builtin_nontemporal_store(ov, &out4[idx]); \
        idx += s; \
    } while (0)

    // Prologue: fill the 4-deep pipeline (uniform guards; T is scalar).
    f4 x0 = (f4)(0.0f);
    f4 x1 = x0, x2 = x0, x3 = x0;
    if (T > 0) x0 = __builtin_nontemporal_load(&x4[idx]);
    if (T > 1) x1 = __builtin_nontemporal_load(&x4[idx + s]);
    if (T > 2) x2 = __builtin_nontemporal_load(&x4[idx + 2 * s]);
    if (T > 3) x3 = __builtin_nontemporal_load(&x4[idx + 3 * s]);

    int t = 0;
    for (; t + 8 <= T; t += 4) {
        // Issue next 4 prefetches first — independent, so they overlap the
        // ~4 steps (~800+ cycles) of dependent tanh/exp compute below.
        const size_t pf = idx + 4 * s;
        f4 n0 = __builtin_nontemporal_load(&x4[pf]);
        f4 n1 = __builtin_nontemporal_load(&x4[pf + s]);
        f4 n2 = __builtin_nontemporal_load(&x4[pf + 2 * s]);
        f4 n3 = __builtin_nontemporal_load(&x4[pf + 3 * s]);

        STEP(x0); STEP(x1); STEP(x2); STEP(x3);

        x0 = n0; x1 = n1; x2 = n2; x3 = n3;
    }

    // Epilogue: 4..7 steps remain (or all of T when T < 8).
    int rem = T - t;
    if (rem > 0) STEP(x0);
    if (rem > 1) STEP(x1);
    if (rem > 2) STEP(x2);
    if (rem > 3) STEP(x3);
    for (int i = 4; i < rem; ++i) {
        f4 xv = __builtin_nontemporal_load(&x4[idx]);
        STEP(xv);
    }
#undef STEP

    // hidden state (1, B, 2) appended after out (regular store — it's read back)
    f4 hout;
    hout.x = ha0; hout.y = ha1; hout.z = hb0; hout.w = hb1;
    out4[(size_t)T * s + (size_t)p] = hout;
}

extern "C" void kernel_launch(void* const* d_in, const int* in_sizes, int n_in,
                              void* d_out, int out_size, void* d_ws, size_t ws_size,
                              hipStream_t stream) {
    const float* x    = (const float*)d_in[0];
    const float* h0   = (const float*)d_in[1];
    const float* W_ih = (const float*)d_in[2];
    const float* W_hh = (const float*)d_in[3];
    const float* b_ih = (const float*)d_in[4];
    const float* b_hh = (const float*)d_in[5];
    float* out = (float*)d_out;

    const int BH = in_sizes[1];        // B * H  (H = 2)
    const int B  = BH / 2;
    const int T  = in_sizes[0] / (B * 2);  // I = 2

    const int npairs = B / 2;
    dim3 grid((npairs + TPB - 1) / TPB);
    Pixel_RNNcontrol_75453985456217_kernel<<<grid, TPB, 0, stream>>>(
        x, h0, W_ih, W_hh, b_ih, b_hh, out, T, B);
}